// Round 1
// baseline (281.382 us; speedup 1.0000x reference)
//
#include <hip/hip_runtime.h>
#include <hip/hip_bf16.h>
#include <stdint.h>
#include <stddef.h>

// Problem: B=4096, E=16, D=512, H=2048
// out[b,h] = sum_e relu( x_b . W[e,h,:] - c_e . W[e,h,:] + b[e,h] )
// GEMM view: M=4096, N=E*H (expert-looped), K=512. 137.4 GFLOP, compute-bound.

#define B_DIM 4096
#define E_DIM 16
#define D_DIM 512
#define H_DIM 2048

typedef short bf16x8 __attribute__((ext_vector_type(8)));
typedef float f32x4 __attribute__((ext_vector_type(4)));

__device__ __forceinline__ short f2bf(float f) {
  __hip_bfloat16 h = __float2bfloat16(f);  // RNE
  return *reinterpret_cast<short*>(&h);
}

__device__ __forceinline__ bf16x8 cvt8(float4 a, float4 b) {
  bf16x8 v;
  v[0] = f2bf(a.x); v[1] = f2bf(a.y); v[2] = f2bf(a.z); v[3] = f2bf(a.w);
  v[4] = f2bf(b.x); v[5] = f2bf(b.y); v[6] = f2bf(b.z); v[7] = f2bf(b.w);
  return v;
}

// async global->LDS, 16 bytes per lane. LDS dest must be uniform_base + lane*16.
__device__ __forceinline__ void async_copy16(const void* gptr, void* lptr) {
  __builtin_amdgcn_global_load_lds(
      (const __attribute__((address_space(1))) void*)gptr,
      (__attribute__((address_space(3))) void*)lptr,
      16, 0, 0);
}

// ---------------------------------------------------------------------------
// Prepass 1: one wave per W row (e,h). Converts the 512-float row to bf16 and
// computes bias2[e,h] = b[e,h] - dot(c_e, W[e,h,:]) in fp32.
// Grid: 32768 waves = 8192 blocks x 256 threads (exact, no stragglers).
// ---------------------------------------------------------------------------
__global__ __launch_bounds__(256) void prep_w(
    const float* __restrict__ W, const float* __restrict__ C,
    const float* __restrict__ bias, __hip_bfloat16* __restrict__ Wb,
    float* __restrict__ bias2) {
  const int gw = (blockIdx.x * 256 + threadIdx.x) >> 6;  // wave id == row id
  const int lane = threadIdx.x & 63;
  const int e = gw >> 11;  // / H_DIM

  const float* wr = W + (size_t)gw * D_DIM + lane * 8;
  const float* cr = C + (size_t)e * D_DIM + lane * 8;
  float4 w0 = *(const float4*)(wr);
  float4 w1 = *(const float4*)(wr + 4);
  float4 c0 = *(const float4*)(cr);
  float4 c1 = *(const float4*)(cr + 4);

  *(bf16x8*)((__hip_bfloat16*)Wb + (size_t)gw * D_DIM + lane * 8) = cvt8(w0, w1);

  float dot = w0.x * c0.x + w0.y * c0.y + w0.z * c0.z + w0.w * c0.w +
              w1.x * c1.x + w1.y * c1.y + w1.z * c1.z + w1.w * c1.w;
#pragma unroll
  for (int off = 32; off > 0; off >>= 1) dot += __shfl_down(dot, off, 64);
  if (lane == 0) bias2[gw] = bias[gw] - dot;
}

// ---------------------------------------------------------------------------
// Prepass 2: convert x to bf16. 2M elems, 8 per thread -> 1024 blocks exact.
// ---------------------------------------------------------------------------
__global__ __launch_bounds__(256) void conv_x(
    const float* __restrict__ X, __hip_bfloat16* __restrict__ Xb) {
  const size_t i = ((size_t)blockIdx.x * 256 + threadIdx.x) * 8;
  float4 a = *(const float4*)(X + i);
  float4 b = *(const float4*)(X + i + 4);
  *(bf16x8*)(Xb + i) = cvt8(a, b);
}

// ---------------------------------------------------------------------------
// Main kernel: 128x128 tile per block, 4 waves, each 64x64 via 4x4 MFMA
// 16x16x32 bf16. Expert loop outer; per-expert relu+bias into sum regs.
// Grid = 512 blocks (32 m-tiles x 16 h-tiles) = 2 blocks/CU, all resident.
// ---------------------------------------------------------------------------
__global__ __launch_bounds__(256, 2) void moe_gemm(
    const __hip_bfloat16* __restrict__ Xb,   // [4096, 512]
    const __hip_bfloat16* __restrict__ Wb,   // [16, 2048, 512]
    const float* __restrict__ bias2,         // [16, 2048]
    float* __restrict__ out) {               // [4096, 2048]
  __shared__ __align__(16) __hip_bfloat16 As[128 * 32];  // 8 KB
  __shared__ __align__(16) __hip_bfloat16 Bs[128 * 32];  // 8 KB
  __shared__ __align__(16) float biasS[E_DIM * 128];     // 8 KB

  const int tid = threadIdx.x;
  const int lane = tid & 63;
  const int wave = tid >> 6;
  const int hi = blockIdx.x & 15;   // same-hi blocks share blockIdx%8 -> same XCD
  const int mi = blockIdx.x >> 4;
  const int m0 = mi * 128;
  const int h0 = hi * 128;

  // preload bias2 for this h-tile, all experts
  for (int idx = tid; idx < E_DIM * 128; idx += 256) {
    biasS[idx] = bias2[((idx >> 7) << 11) + h0 + (idx & 127)];
  }

  const int wm = (wave & 1) * 64;
  const int wn = (wave >> 1) * 64;
  const int lm = lane & 15;
  const int lk = (lane >> 4) * 8;

  // staging: 128x32 bf16 = 8 KB = 512 chunks of 16B; thread t does chunks t, t+256
  const int ar0 = tid >> 2;                 // rows 0..63
  const int ar1 = (tid + 256) >> 2;         // rows 64..127
  const int ac = (tid & 3) << 3;            // col offset 0/8/16/24

  const __hip_bfloat16* Arow0 = Xb + (size_t)(m0 + ar0) * D_DIM + ac;
  const __hip_bfloat16* Arow1 = Xb + (size_t)(m0 + ar1) * D_DIM + ac;

  f32x4 sum[4][4];
#pragma unroll
  for (int i = 0; i < 4; ++i)
#pragma unroll
    for (int j = 0; j < 4; ++j) sum[i][j] = (f32x4){0.f, 0.f, 0.f, 0.f};

  for (int e = 0; e < E_DIM; ++e) {
    const __hip_bfloat16* Wrow0 = Wb + ((size_t)e * H_DIM + h0 + ar0) * D_DIM + ac;
    const __hip_bfloat16* Wrow1 = Wb + ((size_t)e * H_DIM + h0 + ar1) * D_DIM + ac;

    f32x4 acc[4][4];
#pragma unroll
    for (int i = 0; i < 4; ++i)
#pragma unroll
      for (int j = 0; j < 4; ++j) acc[i][j] = (f32x4){0.f, 0.f, 0.f, 0.f};

    for (int k = 0; k < D_DIM; k += 32) {
      __syncthreads();  // protect LDS from previous iteration's readers
      async_copy16(Arow0 + k, &As[(size_t)tid * 8]);
      async_copy16(Arow1 + k, &As[(size_t)(tid + 256) * 8]);
      async_copy16(Wrow0 + k, &Bs[(size_t)tid * 8]);
      async_copy16(Wrow1 + k, &Bs[(size_t)(tid + 256) * 8]);
      __syncthreads();  // compiler emits vmcnt(0) drain here

      bf16x8 af[4], bfr[4];
#pragma unroll
      for (int i = 0; i < 4; ++i)
        af[i] = *(const bf16x8*)&As[(wm + i * 16 + lm) * 32 + lk];
#pragma unroll
      for (int j = 0; j < 4; ++j)
        bfr[j] = *(const bf16x8*)&Bs[(wn + j * 16 + lm) * 32 + lk];
#pragma unroll
      for (int i = 0; i < 4; ++i)
#pragma unroll
        for (int j = 0; j < 4; ++j)
          acc[i][j] = __builtin_amdgcn_mfma_f32_16x16x32_bf16(
              af[i], bfr[j], acc[i][j], 0, 0, 0);
    }

    // per-expert epilogue: relu(acc + bias2) accumulated into sum
    float bv[4];
#pragma unroll
    for (int j = 0; j < 4; ++j) bv[j] = biasS[e * 128 + wn + j * 16 + lm];
#pragma unroll
    for (int i = 0; i < 4; ++i)
#pragma unroll
      for (int j = 0; j < 4; ++j)
#pragma unroll
        for (int r = 0; r < 4; ++r)
          sum[i][j][r] += fmaxf(acc[i][j][r] + bv[j], 0.f);
  }

  // write: C/D layout col=lane&15, row=(lane>>4)*4+reg  [verified m89/m91]
  const int rbase = (lane >> 4) * 4;
#pragma unroll
  for (int i = 0; i < 4; ++i)
#pragma unroll
    for (int j = 0; j < 4; ++j)
#pragma unroll
      for (int r = 0; r < 4; ++r)
        out[(size_t)(m0 + wm + i * 16 + rbase + r) * H_DIM + h0 + wn + j * 16 + lm] =
            sum[i][j][r];
}

// ---------------------------------------------------------------------------
// Fallback (only if workspace too small): naive but correct fp32.
// ---------------------------------------------------------------------------
__global__ __launch_bounds__(256) void naive_kernel(
    const float* __restrict__ x, const float* __restrict__ c,
    const float* __restrict__ W, const float* __restrict__ bias,
    float* __restrict__ out) {
  const int idx = blockIdx.x * 256 + threadIdx.x;
  const int b = idx >> 11;
  const int h = idx & (H_DIM - 1);
  const float* xr = x + (size_t)b * D_DIM;
  float s = 0.f;
  for (int e = 0; e < E_DIM; ++e) {
    const float* wr = W + ((size_t)e * H_DIM + h) * D_DIM;
    const float* cr = c + (size_t)e * D_DIM;
    float acc = bias[e * H_DIM + h];
    for (int d = 0; d < D_DIM; ++d) acc += (xr[d] - cr[d]) * wr[d];
    s += fmaxf(acc, 0.f);
  }
  out[idx] = s;
}

extern "C" void kernel_launch(void* const* d_in, const int* in_sizes, int n_in,
                              void* d_out, int out_size, void* d_ws, size_t ws_size,
                              hipStream_t stream) {
  const float* x = (const float*)d_in[0];     // [4096, 512]
  const float* c = (const float*)d_in[1];     // [16, 512]
  const float* W = (const float*)d_in[2];     // [16, 2048, 512]
  const float* b = (const float*)d_in[3];     // [16, 2048]
  float* out = (float*)d_out;                 // [4096, 2048]

  const size_t sz_wb = (size_t)E_DIM * H_DIM * D_DIM * 2;  // 32 MB
  const size_t sz_xb = (size_t)B_DIM * D_DIM * 2;          // 4 MB
  const size_t sz_b2 = (size_t)E_DIM * H_DIM * 4;          // 128 KB
  const size_t need = sz_wb + sz_xb + sz_b2;

  if (ws_size >= need) {
    __hip_bfloat16* Wb = (__hip_bfloat16*)((char*)d_ws);
    __hip_bfloat16* Xb = (__hip_bfloat16*)((char*)d_ws + sz_wb);
    float* bias2 = (float*)((char*)d_ws + sz_wb + sz_xb);
    prep_w<<<8192, 256, 0, stream>>>(W, c, b, Wb, bias2);
    conv_x<<<1024, 256, 0, stream>>>(x, Xb);
    moe_gemm<<<512, 256, 0, stream>>>(Xb, Wb, bias2, out);
  } else {
    naive_kernel<<<(B_DIM * H_DIM) / 256, 256, 0, stream>>>(x, c, W, b, out);
  }
}

// Round 2
// 262.004 us; speedup vs baseline: 1.0740x; 1.0740x over previous
//
#include <hip/hip_runtime.h>
#include <hip/hip_bf16.h>
#include <stdint.h>
#include <stddef.h>

// Problem: B=4096, E=16, D=512, H=2048
// out[b,h] = sum_e relu( x_b . W[e,h,:] - c_e . W[e,h,:] + b[e,h] )
// GEMM view: M=4096, N=E*H (expert-looped), K=512. 137.4 GFLOP, compute-bound.
// MFMA floor: 32768 MFMA/CU * 4.8cyc = 65 us.

#define B_DIM 4096
#define E_DIM 16
#define D_DIM 512
#define H_DIM 2048

typedef short bf16x8 __attribute__((ext_vector_type(8)));
typedef float f32x4 __attribute__((ext_vector_type(4)));

__device__ __forceinline__ short f2bf(float f) {
  __hip_bfloat16 h = __float2bfloat16(f);  // RNE
  return *reinterpret_cast<short*>(&h);
}

__device__ __forceinline__ bf16x8 cvt8(float4 a, float4 b) {
  bf16x8 v;
  v[0] = f2bf(a.x); v[1] = f2bf(a.y); v[2] = f2bf(a.z); v[3] = f2bf(a.w);
  v[4] = f2bf(b.x); v[5] = f2bf(b.y); v[6] = f2bf(b.z); v[7] = f2bf(b.w);
  return v;
}

// async global->LDS, 16 bytes per lane. LDS dest must be uniform_base + lane*16.
__device__ __forceinline__ void async_copy16(const void* gptr, void* lptr) {
  __builtin_amdgcn_global_load_lds(
      (const __attribute__((address_space(1))) void*)gptr,
      (__attribute__((address_space(3))) void*)lptr,
      16, 0, 0);
}

// ---------------------------------------------------------------------------
// Prepass 1: one wave per W row (e,h): convert row to bf16, compute
// bias2[e,h] = b[e,h] - dot(c_e, W[e,h,:]).
// ---------------------------------------------------------------------------
__global__ __launch_bounds__(256) void prep_w(
    const float* __restrict__ W, const float* __restrict__ C,
    const float* __restrict__ bias, __hip_bfloat16* __restrict__ Wb,
    float* __restrict__ bias2) {
  const int gw = (blockIdx.x * 256 + threadIdx.x) >> 6;  // wave id == row id
  const int lane = threadIdx.x & 63;
  const int e = gw >> 11;  // / H_DIM

  const float* wr = W + (size_t)gw * D_DIM + lane * 8;
  const float* cr = C + (size_t)e * D_DIM + lane * 8;
  float4 w0 = *(const float4*)(wr);
  float4 w1 = *(const float4*)(wr + 4);
  float4 c0 = *(const float4*)(cr);
  float4 c1 = *(const float4*)(cr + 4);

  *(bf16x8*)((__hip_bfloat16*)Wb + (size_t)gw * D_DIM + lane * 8) = cvt8(w0, w1);

  float dot = w0.x * c0.x + w0.y * c0.y + w0.z * c0.z + w0.w * c0.w +
              w1.x * c1.x + w1.y * c1.y + w1.z * c1.z + w1.w * c1.w;
#pragma unroll
  for (int off = 32; off > 0; off >>= 1) dot += __shfl_down(dot, off, 64);
  if (lane == 0) bias2[gw] = bias[gw] - dot;
}

// ---------------------------------------------------------------------------
// Prepass 2: convert x to bf16. 2M elems, 8 per thread -> 1024 blocks exact.
// ---------------------------------------------------------------------------
__global__ __launch_bounds__(256) void conv_x(
    const float* __restrict__ X, __hip_bfloat16* __restrict__ Xb) {
  const size_t i = ((size_t)blockIdx.x * 256 + threadIdx.x) * 8;
  float4 a = *(const float4*)(X + i);
  float4 b = *(const float4*)(X + i + 4);
  *(bf16x8*)(Xb + i) = cvt8(a, b);
}

// ---------------------------------------------------------------------------
// Main kernel: 128x128 tile, 4 waves x 64x64, 2 experts per K-pass (shared
// A staging + A-fragments), XOR-swizzled LDS to kill bank conflicts.
// Grid = 512 blocks = 2 blocks/CU all resident.
// Swizzle: LDS chunk (row r, ql) holds global k-chunk (ql ^ f(r)),
// f(r) = (r ^ (r>>2)) & 3. Read of (row, q) fetches chunk q ^ f(row).
// ---------------------------------------------------------------------------
__global__ __launch_bounds__(256, 2) void moe_gemm(
    const __hip_bfloat16* __restrict__ Xb,   // [4096, 512]
    const __hip_bfloat16* __restrict__ Wb,   // [16, 2048, 512]
    const float* __restrict__ bias2,         // [16, 2048]
    float* __restrict__ out) {               // [4096, 2048]
  __shared__ __align__(16) __hip_bfloat16 As[128 * 32];   // 8 KB
  __shared__ __align__(16) __hip_bfloat16 Bs0[128 * 32];  // 8 KB
  __shared__ __align__(16) __hip_bfloat16 Bs1[128 * 32];  // 8 KB
  __shared__ __align__(16) float biasS[E_DIM * 128];      // 8 KB

  const int tid = threadIdx.x;
  const int lane = tid & 63;
  const int wave = tid >> 6;
  const int hi = blockIdx.x & 15;
  const int mi = blockIdx.x >> 4;
  const int m0 = mi * 128;
  const int h0 = hi * 128;

  // preload bias2 for this h-tile, all experts
  for (int idx = tid; idx < E_DIM * 128; idx += 256) {
    biasS[idx] = bias2[((idx >> 7) << 11) + h0 + (idx & 127)];
  }

  const int wm = (wave & 1) * 64;
  const int wn = (wave >> 1) * 64;
  const int lm = lane & 15;
  const int q = lane >> 4;

  // ---- staging precompute (chunks tid and tid+256; rows r and r+64 share f)
  const int r = tid >> 2;
  const int ql = tid & 3;
  const int fr = (r ^ (r >> 2)) & 3;
  const int srcCol = ((ql ^ fr) << 3);  // element offset of the k-chunk we fetch

  const __hip_bfloat16* Asrc0 = Xb + (size_t)(m0 + r) * D_DIM + srcCol;
  const __hip_bfloat16* Asrc1 = Xb + (size_t)(m0 + r + 64) * D_DIM + srcCol;
  const size_t brow0 = (size_t)(h0 + r) * D_DIM + srcCol;
  const size_t brow1 = (size_t)(h0 + r + 64) * D_DIM + srcCol;

  // ---- read-side precomputed element offsets (swizzled), fixed per lane
  int offA[4], offB[4];
#pragma unroll
  for (int i = 0; i < 4; ++i) {
    const int R = wm + i * 16 + lm;
    const int f = (R ^ (R >> 2)) & 3;
    offA[i] = R * 32 + ((q ^ f) << 3);
  }
#pragma unroll
  for (int j = 0; j < 4; ++j) {
    const int R = wn + j * 16 + lm;
    const int f = (R ^ (R >> 2)) & 3;
    offB[j] = R * 32 + ((q ^ f) << 3);
  }

  f32x4 sum[4][4];
#pragma unroll
  for (int i = 0; i < 4; ++i)
#pragma unroll
    for (int j = 0; j < 4; ++j) sum[i][j] = (f32x4){0.f, 0.f, 0.f, 0.f};

  for (int ep = 0; ep < E_DIM / 2; ++ep) {
    const __hip_bfloat16* B0 = Wb + ((size_t)(2 * ep) << 20);      // e*H*D
    const __hip_bfloat16* B1 = Wb + ((size_t)(2 * ep + 1) << 20);

    f32x4 acc0[4][4], acc1[4][4];
#pragma unroll
    for (int i = 0; i < 4; ++i)
#pragma unroll
      for (int j = 0; j < 4; ++j) {
        acc0[i][j] = (f32x4){0.f, 0.f, 0.f, 0.f};
        acc1[i][j] = (f32x4){0.f, 0.f, 0.f, 0.f};
      }

    for (int k = 0; k < D_DIM; k += 32) {
      __syncthreads();  // protect LDS from previous iteration's readers
      async_copy16(Asrc0 + k, &As[(size_t)tid * 8]);
      async_copy16(Asrc1 + k, &As[(size_t)(tid + 256) * 8]);
      async_copy16(B0 + brow0 + k, &Bs0[(size_t)tid * 8]);
      async_copy16(B0 + brow1 + k, &Bs0[(size_t)(tid + 256) * 8]);
      async_copy16(B1 + brow0 + k, &Bs1[(size_t)tid * 8]);
      async_copy16(B1 + brow1 + k, &Bs1[(size_t)(tid + 256) * 8]);
      __syncthreads();  // vmcnt(0) drain: LDS ready

      bf16x8 af[4];
#pragma unroll
      for (int i = 0; i < 4; ++i) af[i] = *(const bf16x8*)&As[offA[i]];
#pragma unroll
      for (int j = 0; j < 4; ++j) {
        const bf16x8 b0 = *(const bf16x8*)&Bs0[offB[j]];
#pragma unroll
        for (int i = 0; i < 4; ++i)
          acc0[i][j] = __builtin_amdgcn_mfma_f32_16x16x32_bf16(
              af[i], b0, acc0[i][j], 0, 0, 0);
        const bf16x8 b1 = *(const bf16x8*)&Bs1[offB[j]];
#pragma unroll
        for (int i = 0; i < 4; ++i)
          acc1[i][j] = __builtin_amdgcn_mfma_f32_16x16x32_bf16(
              af[i], b1, acc1[i][j], 0, 0, 0);
      }
    }

    // epilogue: relu both experts, accumulate into sum
#pragma unroll
    for (int j = 0; j < 4; ++j) {
      const float bv0 = biasS[(2 * ep) * 128 + wn + j * 16 + lm];
      const float bv1 = biasS[(2 * ep + 1) * 128 + wn + j * 16 + lm];
#pragma unroll
      for (int i = 0; i < 4; ++i)
#pragma unroll
        for (int t = 0; t < 4; ++t)
          sum[i][j][t] += fmaxf(acc0[i][j][t] + bv0, 0.f) +
                          fmaxf(acc1[i][j][t] + bv1, 0.f);
    }
  }

  // write: C/D layout col=lane&15, row=(lane>>4)*4+reg  [verified m89/m91]
  const int rbase = q * 4;
#pragma unroll
  for (int i = 0; i < 4; ++i)
#pragma unroll
    for (int j = 0; j < 4; ++j)
#pragma unroll
      for (int t = 0; t < 4; ++t)
        out[(size_t)(m0 + wm + i * 16 + rbase + t) * H_DIM + h0 + wn + j * 16 + lm] =
            sum[i][j][t];
}

// ---------------------------------------------------------------------------
// Fallback (only if workspace too small): naive but correct fp32.
// ---------------------------------------------------------------------------
__global__ __launch_bounds__(256) void naive_kernel(
    const float* __restrict__ x, const float* __restrict__ c,
    const float* __restrict__ W, const float* __restrict__ bias,
    float* __restrict__ out) {
  const int idx = blockIdx.x * 256 + threadIdx.x;
  const int b = idx >> 11;
  const int h = idx & (H_DIM - 1);
  const float* xr = x + (size_t)b * D_DIM;
  float s = 0.f;
  for (int e = 0; e < E_DIM; ++e) {
    const float* wr = W + ((size_t)e * H_DIM + h) * D_DIM;
    const float* cr = c + (size_t)e * D_DIM;
    float acc = bias[e * H_DIM + h];
    for (int d = 0; d < D_DIM; ++d) acc += (xr[d] - cr[d]) * wr[d];
    s += fmaxf(acc, 0.f);
  }
  out[idx] = s;
}

extern "C" void kernel_launch(void* const* d_in, const int* in_sizes, int n_in,
                              void* d_out, int out_size, void* d_ws, size_t ws_size,
                              hipStream_t stream) {
  const float* x = (const float*)d_in[0];     // [4096, 512]
  const float* c = (const float*)d_in[1];     // [16, 512]
  const float* W = (const float*)d_in[2];     // [16, 2048, 512]
  const float* b = (const float*)d_in[3];     // [16, 2048]
  float* out = (float*)d_out;                 // [4096, 2048]

  const size_t sz_wb = (size_t)E_DIM * H_DIM * D_DIM * 2;  // 32 MB
  const size_t sz_xb = (size_t)B_DIM * D_DIM * 2;          // 4 MB
  const size_t sz_b2 = (size_t)E_DIM * H_DIM * 4;          // 128 KB
  const size_t need = sz_wb + sz_xb + sz_b2;

  if (ws_size >= need) {
    __hip_bfloat16* Wb = (__hip_bfloat16*)((char*)d_ws);
    __hip_bfloat16* Xb = (__hip_bfloat16*)((char*)d_ws + sz_wb);
    float* bias2 = (float*)((char*)d_ws + sz_wb + sz_xb);
    prep_w<<<8192, 256, 0, stream>>>(W, c, b, Wb, bias2);
    conv_x<<<1024, 256, 0, stream>>>(x, Xb);
    moe_gemm<<<512, 256, 0, stream>>>(Xb, Wb, bias2, out);
  } else {
    naive_kernel<<<(B_DIM * H_DIM) / 256, 256, 0, stream>>>(x, c, W, b, out);
  }
}